// Round 10
// baseline (295.311 us; speedup 1.0000x reference)
//
#include <hip/hip_runtime.h>
#include <cstdint>

#define B_   2
#define L_   2048
#define D_   512
#define H_   8
#define DH_  64
#define DFC_ 2048

typedef unsigned short ushort_t;
typedef __attribute__((ext_vector_type(8))) short bf16x8;
typedef __attribute__((ext_vector_type(4))) short bf16x4;
typedef __attribute__((ext_vector_type(4))) float f32x4;

#define MFMA32(A, Bv, C) __builtin_amdgcn_mfma_f32_16x16x32_bf16(A, Bv, C, 0, 0, 0)
#define MFMA16(A, Bv, C) __builtin_amdgcn_mfma_f32_16x16x16bf16_1k(A, Bv, C, 0, 0, 0)

__device__ __forceinline__ ushort_t f32_bf16(float f) {
  unsigned u = __float_as_uint(f);
  u += 0x7FFFu + ((u >> 16) & 1u);   // round-to-nearest-even
  return (ushort_t)(u >> 16);
}
__device__ __forceinline__ float bf16_f32(ushort_t u) {
  return __uint_as_float(((unsigned)u) << 16);
}

__device__ __forceinline__ void gl_lds16(const ushort_t* g, ushort_t* l) {
  __builtin_amdgcn_global_load_lds(
      (const __attribute__((address_space(1))) void*)(const void*)g,
      (__attribute__((address_space(3))) void*)l, 16, 0, 0);
}

// ---------------------------------------------------------------------------
// ALL packs in one launch. bid<1024: x->bf16; <1536: rel->bf16; else weightT.
// ---------------------------------------------------------------------------
__global__ __launch_bounds__(256)
void pack_all(const float* __restrict__ x, const float* __restrict__ rel,
              const float* __restrict__ wq, const float* __restrict__ wk,
              const float* __restrict__ wv, const float* __restrict__ w1,
              const float* __restrict__ w2,
              ushort_t* __restrict__ xb, ushort_t* __restrict__ relb,
              ushort_t* __restrict__ wqkvT, ushort_t* __restrict__ w1T,
              ushort_t* __restrict__ w2T) {
  __shared__ float T[64 * 65];
  const int bid = blockIdx.x;
  const int t = threadIdx.x;
  if (bid < 1536) {
    const float* in = (bid < 1024) ? x : rel;
    ushort_t* out = (bid < 1024) ? xb : relb;
    const int base = (bid < 1024) ? bid : (bid - 1024);
    int i = (base * 256 + t) * 8;
    float4 a = *(const float4*)(in + i);
    float4 b = *(const float4*)(in + i + 4);
    union { bf16x8 v; ushort_t s[8]; } u;
    u.s[0] = f32_bf16(a.x); u.s[1] = f32_bf16(a.y);
    u.s[2] = f32_bf16(a.z); u.s[3] = f32_bf16(a.w);
    u.s[4] = f32_bf16(b.x); u.s[5] = f32_bf16(b.y);
    u.s[6] = f32_bf16(b.z); u.s[7] = f32_bf16(b.w);
    *(bf16x8*)(out + i) = u.v;
    return;
  }
  const int id = bid - 1536;
  const float* in; ushort_t* out; int K, N, bx, by;
  if (id < 192) {
    int z = id >> 6, r = id & 63;
    in = (z == 0) ? wq : (z == 1) ? wk : wv;
    out = wqkvT + (size_t)z * 512 * 512;
    K = 512; N = 512; bx = r & 7; by = r >> 3;
  } else if (id < 448) {
    int r = id - 192;
    in = w1; out = w1T; K = 512; N = 2048; bx = r & 31; by = r >> 5;
  } else {
    int r = id - 448;
    in = w2; out = w2T; K = 2048; N = 512; bx = r & 7; by = r >> 3;
  }
  const int n0 = bx * 64, k0 = by * 64;
  {
    const int kr = t >> 2, c0 = (t & 3) * 16;
    const float* src = in + (size_t)(k0 + kr) * N + n0 + c0;
#pragma unroll
    for (int u = 0; u < 4; ++u) {
      float4 f = *(const float4*)(src + u * 4);
      T[kr * 65 + c0 + u * 4 + 0] = f.x;
      T[kr * 65 + c0 + u * 4 + 1] = f.y;
      T[kr * 65 + c0 + u * 4 + 2] = f.z;
      T[kr * 65 + c0 + u * 4 + 3] = f.w;
    }
  }
  __syncthreads();
  const int nr = t >> 2, kc0 = (t & 3) * 16;
  union { bf16x8 v; ushort_t s[8]; } o0, o1;
#pragma unroll
  for (int j = 0; j < 8; ++j) {
    o0.s[j] = f32_bf16(T[(kc0 + j) * 65 + nr]);
    o1.s[j] = f32_bf16(T[(kc0 + 8 + j) * 65 + nr]);
  }
  ushort_t* dst = out + (size_t)(n0 + nr) * K + k0 + kc0;
  *(bf16x8*)dst = o0.v;
  *(bf16x8*)(dst + 8) = o1.v;
}

// ---------------------------------------------------------------------------
// BARRIER-FREE flat MFMA GEMM: C = A(M,K) @ Bt(N,K)^T. No LDS; each wave owns
// 32Mx64N and streams A/B fragments directly from global (64B/row coalesced,
// L2-resident weights), register-double-buffered one K-step ahead so the
// compiler emits partial vmcnt waits. No __syncthreads -> no vmcnt(0) drain.
// MODE 0: f32 partial (split-K via z); MODE 1: bf16 +bias+relu; MODE 2: QKV.
// ---------------------------------------------------------------------------
template <int MODE>
__global__ __launch_bounds__(256, 4)
void gemm_flat(const ushort_t* __restrict__ A, const ushort_t* __restrict__ Bt,
               const float* __restrict__ b0p, const float* __restrict__ b1p,
               const float* __restrict__ b2p,
               void* __restrict__ out0, void* __restrict__ out1, void* __restrict__ out2,
               int M, int N, int K, int ksplit) {
  const int t  = threadIdx.x;
  const int wv = t >> 6, ln = t & 63;
  const int l16 = ln & 15, lg = ln >> 4;
  const int n0 = blockIdx.x * 128, m0 = blockIdx.y * 64;
  const int mw = (wv >> 1) * 32, nw = (wv & 1) * 64;

  const int kchunk = K / ksplit;
  const int kbeg = blockIdx.z * kchunk, kend = kbeg + kchunk;

  const ushort_t* Ar0 = A + (size_t)(m0 + mw + l16) * K;
  const ushort_t* Ar1 = A + (size_t)(m0 + mw + 16 + l16) * K;
  const ushort_t* Br0 = Bt + (size_t)(n0 + nw + l16) * K;
  const ushort_t* Br1 = Bt + (size_t)(n0 + nw + 16 + l16) * K;
  const ushort_t* Br2 = Bt + (size_t)(n0 + nw + 32 + l16) * K;
  const ushort_t* Br3 = Bt + (size_t)(n0 + nw + 48 + l16) * K;

  f32x4 acc[2][4] = {};

  bf16x8 a0c, a1c, b0c, b1c, b2c, b3c;     // current
  bf16x8 a0n, a1n, b0n, b1n, b2n, b3n;     // next (in flight)
  {
    const int ka = kbeg + lg * 8;
    a0c = *(const bf16x8*)(Ar0 + ka); a1c = *(const bf16x8*)(Ar1 + ka);
    b0c = *(const bf16x8*)(Br0 + ka); b1c = *(const bf16x8*)(Br1 + ka);
    b2c = *(const bf16x8*)(Br2 + ka); b3c = *(const bf16x8*)(Br3 + ka);
  }

  for (int k0 = kbeg; k0 < kend; k0 += 32) {
    if (k0 + 32 < kend) {
      const int ka = k0 + 32 + lg * 8;
      a0n = *(const bf16x8*)(Ar0 + ka); a1n = *(const bf16x8*)(Ar1 + ka);
      b0n = *(const bf16x8*)(Br0 + ka); b1n = *(const bf16x8*)(Br1 + ka);
      b2n = *(const bf16x8*)(Br2 + ka); b3n = *(const bf16x8*)(Br3 + ka);
    }
    acc[0][0] = MFMA32(a0c, b0c, acc[0][0]);
    acc[0][1] = MFMA32(a0c, b1c, acc[0][1]);
    acc[0][2] = MFMA32(a0c, b2c, acc[0][2]);
    acc[0][3] = MFMA32(a0c, b3c, acc[0][3]);
    acc[1][0] = MFMA32(a1c, b0c, acc[1][0]);
    acc[1][1] = MFMA32(a1c, b1c, acc[1][1]);
    acc[1][2] = MFMA32(a1c, b2c, acc[1][2]);
    acc[1][3] = MFMA32(a1c, b3c, acc[1][3]);
    a0c = a0n; a1c = a1n;
    b0c = b0n; b1c = b1n; b2c = b2n; b3c = b3n;
  }

  if (MODE == 0) {
    float* outp = (blockIdx.z == 0) ? (float*)out0 : (float*)out1;
#pragma unroll
    for (int mi = 0; mi < 2; ++mi)
#pragma unroll
      for (int reg = 0; reg < 4; ++reg) {
        const int m = m0 + mw + mi * 16 + lg * 4 + reg;
#pragma unroll
        for (int ni = 0; ni < 4; ++ni) {
          const int c = n0 + nw + ni * 16 + l16;
          outp[(size_t)m * N + c] = acc[mi][ni][reg];
        }
      }
  } else if (MODE == 1) {
    ushort_t* outp = (ushort_t*)out0;
#pragma unroll
    for (int mi = 0; mi < 2; ++mi)
#pragma unroll
      for (int reg = 0; reg < 4; ++reg) {
        const int m = m0 + mw + mi * 16 + lg * 4 + reg;
#pragma unroll
        for (int ni = 0; ni < 4; ++ni) {
          const int c = n0 + nw + ni * 16 + l16;
          float v = acc[mi][ni][reg] + b0p[c];
          outp[(size_t)m * N + c] = f32_bf16(fmaxf(v, 0.f));
        }
      }
  } else {
#pragma unroll
    for (int mi = 0; mi < 2; ++mi)
#pragma unroll
      for (int reg = 0; reg < 4; ++reg) {
        const int m = m0 + mw + mi * 16 + lg * 4 + reg;
        const int b = m >> 11, l = m & (L_ - 1);
#pragma unroll
        for (int ni = 0; ni < 4; ++ni) {
          const int c = n0 + nw + ni * 16 + l16;
          const int which = c >> 9, cc = c & 511;
          const int h = cc >> 6, dh = cc & 63;
          const float* bias = (which == 0) ? b0p : (which == 1) ? b1p : b2p;
          float v = acc[mi][ni][reg] + bias[cc];
          if (which == 0) {
            ((ushort_t*)out0)[(((size_t)b * H_ + h) * L_ + l) * DH_ + dh] =
                f32_bf16(v * 0.125f);                    // q pre-scaled
          } else if (which == 1) {
            ((ushort_t*)out1)[(((size_t)b * H_ + h) * L_ + l) * DH_ + dh] = f32_bf16(v);
          } else {
            ((ushort_t*)out2)[(((size_t)b * H_ + h) * DH_ + dh) * L_ + l] = f32_bf16(v);
          }
        }
      }
  }
}

// ---------------------------------------------------------------------------
// FFN2 split-K combine: out = out + p1 + bias
// ---------------------------------------------------------------------------
__global__ __launch_bounds__(256)
void ffn2_add(float* __restrict__ out, const float* __restrict__ p1,
              const float* __restrict__ bias) {
  int i = (blockIdx.x * 256 + threadIdx.x) * 4;
  float4 a = *(const float4*)(out + i);
  float4 b = *(const float4*)(p1 + i);
  float4 bb = *(const float4*)(bias + (i & (D_ - 1)));
  a.x += b.x + bb.x; a.y += b.y + bb.y;
  a.z += b.z + bb.z; a.w += b.w + bb.w;
  *(float4*)(out + i) = a;
}

// ---------------------------------------------------------------------------
// MFMA flash attention (unchanged from R9): S^T form, dbuf K/V DMA,
// reg-prefetched E, longest-first dispatch, bf16 ring, bf16 partials.
// ---------------------------------------------------------------------------
__global__ __launch_bounds__(256, 3)
void attn_mfma(const ushort_t* __restrict__ q16, const ushort_t* __restrict__ k16,
               const ushort_t* __restrict__ vT, const ushort_t* __restrict__ relb,
               ushort_t* __restrict__ Opart, float* __restrict__ Lpart) {
  __shared__ ushort_t Ks[2][64 * 64];   // [j][dh], 16B chunks swizzled by (j&7)
  __shared__ ushort_t Vs[2][64 * 64];   // [dh][j], 16B chunks swizzled by (dh&7)
  __shared__ ushort_t Rc[64 * 136];     // ring [qrow][col]; 128 cols + pad

  const int t   = threadIdx.x;
  const int wv  = t >> 6;
  const int ln  = t & 63;
  const int l16 = ln & 15;
  const int lg  = ln >> 4;
  const int bh  = blockIdx.x;
  const int yy  = blockIdx.y;
  const int qb  = 31 - ((yy < 16) ? yy : (47 - yy));   // longest blocks first
  const int z   = blockIdx.z;
  const int i0  = qb * 64;
  const int mid = (qb + 2) >> 1;
  const int kbeg = z ? mid : 0;
  const int kend = z ? (qb + 1) : mid;

  const ushort_t* qh = q16 + (size_t)bh * L_ * DH_;
  const ushort_t* kh = k16 + (size_t)bh * L_ * DH_;
  const ushort_t* vh = vT + (size_t)bh * DH_ * L_;
  const ushort_t* relh = relb + (bh & 7) * DH_;

  const int r64i = wv * 16 + l16;
  const int rrow = r64i * 136;

  bf16x8 qf0, qf1;
  {
    const ushort_t* qr = qh + (size_t)(i0 + r64i) * DH_ + lg * 8;
    qf0 = *(const bf16x8*)(qr);
    qf1 = *(const bf16x8*)(qr + 32);
  }

  const f32x4 zf = {0.f, 0.f, 0.f, 0.f};
  f32x4 Of[4] = {zf, zf, zf, zf};
  float lsum = 0.f;
  bf16x8 eA[4], eB[4];

  auto stageKV = [&](int j0, int b) {
#pragma unroll
    for (int i = 0; i < 2; ++i) {
      const int s = (i * 4 + wv) * 64 + ln;
      const int row = s >> 3, c = s & 7;
      const int g = c ^ (row & 7);
      gl_lds16(kh + (size_t)(j0 + row) * DH_ + g * 8, &Ks[b][(i * 4 + wv) * 512]);
      gl_lds16(vh + (size_t)row * L_ + j0 + g * 8, &Vs[b][(i * 4 + wv) * 512]);
    }
  };

  auto load_E = [&](int mbase) {
#pragma unroll
    for (int cb = 0; cb < 4; ++cb) {
      const ushort_t* e = relh + (size_t)(mbase + cb * 16 + l16) * D_ + lg * 8;
      eA[cb] = *(const bf16x8*)(e);
      eB[cb] = *(const bf16x8*)(e + 32);
    }
  };

  auto mfma_R = [&](int slotbase) {
#pragma unroll
    for (int cb = 0; cb < 4; ++cb) {
      f32x4 r = MFMA32(eA[cb], qf0, zf);
      r = MFMA32(eB[cb], qf1, r);
      ushort4 w;
      w.x = f32_bf16(r[0]); w.y = f32_bf16(r[1]);
      w.z = f32_bf16(r[2]); w.w = f32_bf16(r[3]);
      *(ushort4*)&Rc[rrow + slotbase + cb * 16 + lg * 4] = w;
      if (slotbase == 0 && cb == 0 && lg == 0)
        *(ushort4*)&Rc[rrow + 128] = w;   // pad cols 128..131 = ring cols 0..3
    }
  };

  if (kbeg < kend) {
    load_E(L_ - 64 - i0 + kbeg * 64);
    stageKV(kbeg * 64, kbeg & 1);
    mfma_R((kbeg & 1) * 64);
    if (kbeg < qb) load_E(L_ - 64 - i0 + (kbeg + 1) * 64);

    for (int kb = kbeg; kb < kend; ++kb) {
      const int j0 = kb * 64;
      const int buf = kb & 1;
      __syncthreads();
      if (kb + 1 < kend) stageKV(j0 + 64, buf ^ 1);
      if (kb < qb) mfma_R(((kb + 1) & 1) * 64);
      if (kb + 1 < qb) load_E(L_ - 64 - i0 + (kb + 2) * 64);

      f32x4 sf[4];
#pragma unroll
      for (int cb = 0; cb < 4; ++cb) {
        const int j = cb * 16 + l16;
        const int sw = j & 7;
        bf16x8 k0 = *(const bf16x8*)&Ks[buf][j * 64 + ((lg ^ sw) * 8)];
        bf16x8 k1 = *(const bf16x8*)&Ks[buf][j * 64 + (((lg + 4) ^ sw) * 8)];
        f32x4 s = MFMA32(k0, qf0, zf);
        sf[cb] = MFMA32(k1, qf1, s);
      }

      const bool diag = (kb == qb);
      bf16x4 pa[4];
#pragma unroll
      for (int cb = 0; cb < 4; ++cb) {
        const int jj0 = cb * 16 + lg * 4;
        const int base = (j0 + jj0 + 63 - r64i) & 127;
        union { bf16x4 v; ushort_t s[4]; } pk;
#pragma unroll
        for (int reg = 0; reg < 4; ++reg) {
          float x = sf[cb][reg] + bf16_f32(Rc[rrow + base + reg]);
          if (diag && (jj0 + reg) > r64i) x = -1e30f;
          float p = __expf(x);
          lsum += p;
          pk.s[reg] = f32_bf16(p);
        }
        pa[cb] = pk.v;
      }

#pragma unroll
      for (int cb2 = 0; cb2 < 4; ++cb2) {
        const int dh = cb2 * 16 + l16;
        const int sw = dh & 7;
        const ushort_t* vrow = &Vs[buf][dh * 64];
#pragma unroll
        for (int cb = 0; cb < 4; ++cb) {
          const int cc = cb * 2 + (lg >> 1);
          bf16x4 vf = *(const bf16x4*)&vrow[((cc ^ sw) * 8) + (lg & 1) * 4];
          Of[cb2] = MFMA16(vf, pa[cb], Of[cb2]);
        }
      }
    }
  }

  float tot = lsum;
  tot += __shfl_xor(tot, 16);
  tot += __shfl_xor(tot, 32);
  if (lg == 0)
    Lpart[((size_t)(z * 16 + bh)) * L_ + i0 + r64i] = tot;
  ushort_t* orow = Opart + (((size_t)(z * 16 + bh)) * L_ + i0 + r64i) * DH_;
#pragma unroll
  for (int cb2 = 0; cb2 < 4; ++cb2) {
    ushort4 w;
    w.x = f32_bf16(Of[cb2][0]); w.y = f32_bf16(Of[cb2][1]);
    w.z = f32_bf16(Of[cb2][2]); w.w = f32_bf16(Of[cb2][3]);
    *(ushort4*)&orow[cb2 * 16 + lg * 4] = w;
  }
}

// ---------------------------------------------------------------------------
// attn partial combine: attnb = (O0 + O1) / (l0 + l1), bf16 (B,L,D). grid 2048.
// ---------------------------------------------------------------------------
__global__ __launch_bounds__(256)
void attn_combine(const ushort_t* __restrict__ Opart, const float* __restrict__ Lpart,
                  ushort_t* __restrict__ attnb) {
  const int g = blockIdx.x * 256 + threadIdx.x;
  const int dh4 = g & 15, i = (g >> 4) & (L_ - 1), bh = g >> 15;
  const size_t o0 = (((size_t)bh * L_ + i) * DH_) + dh4 * 4;
  const size_t zs = (size_t)16 * L_ * DH_;
  ushort4 a = *(const ushort4*)(Opart + o0);
  ushort4 b = *(const ushort4*)(Opart + o0 + zs);
  const float l = Lpart[(size_t)bh * L_ + i] + Lpart[(size_t)(16 + bh) * L_ + i];
  const float inv = 1.f / l;
  ushort4 o;
  o.x = f32_bf16((bf16_f32(a.x) + bf16_f32(b.x)) * inv);
  o.y = f32_bf16((bf16_f32(a.y) + bf16_f32(b.y)) * inv);
  o.z = f32_bf16((bf16_f32(a.z) + bf16_f32(b.z)) * inv);
  o.w = f32_bf16((bf16_f32(a.w) + bf16_f32(b.w)) * inv);
  const int bb = bh >> 3, h = bh & 7;
  *(ushort4*)(attnb + ((size_t)(bb * L_ + i)) * D_ + h * DH_ + dh4 * 4) = o;
}

// ---------------------------------------------------------------------------
extern "C" void kernel_launch(void* const* d_in, const int* in_sizes, int n_in,
                              void* d_out, int out_size, void* d_ws, size_t ws_size,
                              hipStream_t stream) {
  const float* x   = (const float*)d_in[0];
  const float* wq  = (const float*)d_in[2];
  const float* bq  = (const float*)d_in[3];
  const float* wk  = (const float*)d_in[4];
  const float* bk  = (const float*)d_in[5];
  const float* wv  = (const float*)d_in[6];
  const float* bv  = (const float*)d_in[7];
  const float* rel = (const float*)d_in[8];
  const float* w1  = (const float*)d_in[9];
  const float* b1  = (const float*)d_in[10];
  const float* w2  = (const float*)d_in[11];
  const float* b2  = (const float*)d_in[12];

  char* wsb = (char*)d_ws;
  const size_t MB = 1u << 20;
  ushort_t* xb     = (ushort_t*)(wsb + 0 * MB);    // 4 MB; dead after QKV
  ushort_t* attnb  = (ushort_t*)(wsb + 0 * MB);    // 4 MB; aliases xb
  ushort_t* wqkvT  = (ushort_t*)(wsb + 4 * MB);    // 1.5 MB
  ushort_t* w1T    = (ushort_t*)(wsb + 6 * MB);    // 2 MB
  ushort_t* w2T    = (ushort_t*)(wsb + 8 * MB);    // 2 MB
  ushort_t* relb   = (ushort_t*)(wsb + 10 * MB);   // 2 MB
  ushort_t* q16    = (ushort_t*)(wsb + 12 * MB);   // 4 MB (B,H,L,DH)
  ushort_t* k16    = (ushort_t*)(wsb + 16 * MB);   // 4 MB
  ushort_t* vTb    = (ushort_t*)(wsb + 20 * MB);   // 4 MB (B,H,DH,L)
  ushort_t* Opart  = (ushort_t*)(wsb + 24 * MB);   // 8 MB (2,16,L,DH) bf16
  float*    Lpart  = (float*)(wsb + 40 * MB);      // 256 KB (2,16,L) f32
  ushort_t* hidb   = (ushort_t*)(wsb + 24 * MB);   // 16 MB; clobbers dead Opart
  float*    p1     = (float*)(wsb + 12 * MB);      // 8 MB; clobbers dead q16/k16
  float*    out    = (float*)d_out;

  dim3 blk(256);
  pack_all<<<dim3(2240), blk, 0, stream>>>(x, rel, wq, wk, wv, w1, w2,
                                           xb, relb, wqkvT, w1T, w2T);
  // fused QKV projection; emits q (scaled), k, and v already transposed
  gemm_flat<2><<<dim3(12, 64), blk, 0, stream>>>(
      xb, wqkvT, bq, bk, bv, q16, k16, vTb, B_ * L_, 1536, D_, 1);
  attn_mfma<<<dim3(16, 32, 2), blk, 0, stream>>>(q16, k16, vTb, relb, Opart, Lpart);
  attn_combine<<<dim3(2048), blk, 0, stream>>>(Opart, Lpart, attnb);
  gemm_flat<1><<<dim3(16, 64), blk, 0, stream>>>(
      attnb, w1T, b1, nullptr, nullptr, hidb, nullptr, nullptr,
      B_ * L_, DFC_, D_, 1);
  gemm_flat<0><<<dim3(4, 64, 2), blk, 0, stream>>>(
      hidb, w2T, nullptr, nullptr, nullptr, out, p1, nullptr,
      B_ * L_, D_, DFC_, 2);
  ffn2_add<<<dim3(2048), blk, 0, stream>>>(out, p1, b2);
}

// Round 11
// 215.402 us; speedup vs baseline: 1.3710x; 1.3710x over previous
//
#include <hip/hip_runtime.h>
#include <cstdint>

#define B_   2
#define L_   2048
#define D_   512
#define H_   8
#define DH_  64
#define DFC_ 2048

typedef unsigned short ushort_t;
typedef __attribute__((ext_vector_type(8))) short bf16x8;
typedef __attribute__((ext_vector_type(4))) short bf16x4;
typedef __attribute__((ext_vector_type(4))) float f32x4;

#define MFMA32(A, Bv, C) __builtin_amdgcn_mfma_f32_16x16x32_bf16(A, Bv, C, 0, 0, 0)
#define MFMA16(A, Bv, C) __builtin_amdgcn_mfma_f32_16x16x16bf16_1k(A, Bv, C, 0, 0, 0)

__device__ __forceinline__ ushort_t f32_bf16(float f) {
  unsigned u = __float_as_uint(f);
  u += 0x7FFFu + ((u >> 16) & 1u);   // round-to-nearest-even
  return (ushort_t)(u >> 16);
}
__device__ __forceinline__ float bf16_f32(ushort_t u) {
  return __uint_as_float(((unsigned)u) << 16);
}

__device__ __forceinline__ void gl_lds16(const ushort_t* g, ushort_t* l) {
  __builtin_amdgcn_global_load_lds(
      (const __attribute__((address_space(1))) void*)(const void*)g,
      (__attribute__((address_space(3))) void*)l, 16, 0, 0);
}

// ---------------------------------------------------------------------------
// ALL packs in one launch. bid<1024: x->bf16; <1536: rel->bf16; else weightT.
// ---------------------------------------------------------------------------
__global__ __launch_bounds__(256)
void pack_all(const float* __restrict__ x, const float* __restrict__ rel,
              const float* __restrict__ wq, const float* __restrict__ wk,
              const float* __restrict__ wv, const float* __restrict__ w1,
              const float* __restrict__ w2,
              ushort_t* __restrict__ xb, ushort_t* __restrict__ relb,
              ushort_t* __restrict__ wqkvT, ushort_t* __restrict__ w1T,
              ushort_t* __restrict__ w2T) {
  __shared__ float T[64 * 65];
  const int bid = blockIdx.x;
  const int t = threadIdx.x;
  if (bid < 1536) {
    const float* in = (bid < 1024) ? x : rel;
    ushort_t* out = (bid < 1024) ? xb : relb;
    const int base = (bid < 1024) ? bid : (bid - 1024);
    int i = (base * 256 + t) * 8;
    float4 a = *(const float4*)(in + i);
    float4 b = *(const float4*)(in + i + 4);
    union { bf16x8 v; ushort_t s[8]; } u;
    u.s[0] = f32_bf16(a.x); u.s[1] = f32_bf16(a.y);
    u.s[2] = f32_bf16(a.z); u.s[3] = f32_bf16(a.w);
    u.s[4] = f32_bf16(b.x); u.s[5] = f32_bf16(b.y);
    u.s[6] = f32_bf16(b.z); u.s[7] = f32_bf16(b.w);
    *(bf16x8*)(out + i) = u.v;
    return;
  }
  const int id = bid - 1536;
  const float* in; ushort_t* out; int K, N, bx, by;
  if (id < 192) {
    int z = id >> 6, r = id & 63;
    in = (z == 0) ? wq : (z == 1) ? wk : wv;
    out = wqkvT + (size_t)z * 512 * 512;
    K = 512; N = 512; bx = r & 7; by = r >> 3;
  } else if (id < 448) {
    int r = id - 192;
    in = w1; out = w1T; K = 512; N = 2048; bx = r & 31; by = r >> 5;
  } else {
    int r = id - 448;
    in = w2; out = w2T; K = 2048; N = 512; bx = r & 7; by = r >> 3;
  }
  const int n0 = bx * 64, k0 = by * 64;
  {
    const int kr = t >> 2, c0 = (t & 3) * 16;
    const float* src = in + (size_t)(k0 + kr) * N + n0 + c0;
#pragma unroll
    for (int u = 0; u < 4; ++u) {
      float4 f = *(const float4*)(src + u * 4);
      T[kr * 65 + c0 + u * 4 + 0] = f.x;
      T[kr * 65 + c0 + u * 4 + 1] = f.y;
      T[kr * 65 + c0 + u * 4 + 2] = f.z;
      T[kr * 65 + c0 + u * 4 + 3] = f.w;
    }
  }
  __syncthreads();
  const int nr = t >> 2, kc0 = (t & 3) * 16;
  union { bf16x8 v; ushort_t s[8]; } o0, o1;
#pragma unroll
  for (int j = 0; j < 8; ++j) {
    o0.s[j] = f32_bf16(T[(kc0 + j) * 65 + nr]);
    o1.s[j] = f32_bf16(T[(kc0 + 8 + j) * 65 + nr]);
  }
  ushort_t* dst = out + (size_t)(n0 + nr) * K + k0 + kc0;
  *(bf16x8*)dst = o0.v;
  *(bf16x8*)(dst + 8) = o1.v;
}

// ---------------------------------------------------------------------------
// MFMA GEMM: C = A(M,K) @ Bt(N,K)^T. 64x128 tile, BK=64, 4 waves (each
// 32Mx64N), double-buffered global_load_lds staging, ONE barrier per 64-K
// slab (half the drain points of BK=32). Row=128B=8 chunks, chunk^=(row&7)
// swizzle -> b128 frag reads at <=2-way bank aliasing.
// MODE 0: f32 partial (split-K via z); MODE 1: bf16 +bias+relu; MODE 2: QKV.
// ---------------------------------------------------------------------------
template <int MODE>
__global__ __launch_bounds__(256, 3)
void gemm_mfma(const ushort_t* __restrict__ A, const ushort_t* __restrict__ Bt,
               const float* __restrict__ b0p, const float* __restrict__ b1p,
               const float* __restrict__ b2p,
               void* __restrict__ out0, void* __restrict__ out1, void* __restrict__ out2,
               int M, int N, int K, int ksplit) {
  __shared__ ushort_t As[2][64 * 64];    // 64 rows x 64 (BK) ushorts
  __shared__ ushort_t Bs[2][128 * 64];   // 128 rows x 64

  const int t  = threadIdx.x;
  const int wv = t >> 6, ln = t & 63;
  const int l16 = ln & 15, lg = ln >> 4;
  const int n0 = blockIdx.x * 128, m0 = blockIdx.y * 64;
  const int mw = (wv >> 1) * 32, nw = (wv & 1) * 64;

  const int kchunk = K / ksplit;
  const int kbeg = blockIdx.z * kchunk, kend = kbeg + kchunk;

  f32x4 acc[2][4] = {};

  auto stage = [&](int k0, int b) {
#pragma unroll
    for (int i = 0; i < 2; ++i) {                 // A: 512 chunks, 2/thread
      const int s = (i * 4 + wv) * 64 + ln;
      const int row = s >> 3, c = s & 7;
      const int g = c ^ (row & 7);
      gl_lds16(A + (size_t)(m0 + row) * K + k0 + g * 8, &As[b][(i * 4 + wv) * 512]);
    }
#pragma unroll
    for (int i = 0; i < 4; ++i) {                 // B: 1024 chunks, 4/thread
      const int s = (i * 4 + wv) * 64 + ln;
      const int row = s >> 3, c = s & 7;
      const int g = c ^ (row & 7);
      gl_lds16(Bt + (size_t)(n0 + row) * K + k0 + g * 8, &Bs[b][(i * 4 + wv) * 512]);
    }
  };

  stage(kbeg, 0);
  int buf = 0;
  for (int k0 = kbeg; k0 < kend; k0 += 64) {
    __syncthreads();                     // drains DMA(k0) (issued 1 iter ago)
    if (k0 + 64 < kend) stage(k0 + 64, buf ^ 1);

    bf16x8 af[2][2], bfr[2][4];
#pragma unroll
    for (int sub = 0; sub < 2; ++sub) {
#pragma unroll
      for (int mi = 0; mi < 2; ++mi) {
        const int ri = mw + mi * 16 + l16;
        const int g = (sub * 4 + lg) ^ (ri & 7);
        af[sub][mi] = *(const bf16x8*)&As[buf][ri * 64 + g * 8];
      }
#pragma unroll
      for (int ni = 0; ni < 4; ++ni) {
        const int rj = nw + ni * 16 + l16;
        const int g = (sub * 4 + lg) ^ (rj & 7);
        bfr[sub][ni] = *(const bf16x8*)&Bs[buf][rj * 64 + g * 8];
      }
    }
#pragma unroll
    for (int sub = 0; sub < 2; ++sub)
#pragma unroll
      for (int mi = 0; mi < 2; ++mi)
#pragma unroll
        for (int ni = 0; ni < 4; ++ni)
          acc[mi][ni] = MFMA32(af[sub][mi], bfr[sub][ni], acc[mi][ni]);
    buf ^= 1;
  }

  if (MODE == 0) {
    float* outp = (blockIdx.z == 0) ? (float*)out0 : (float*)out1;
#pragma unroll
    for (int mi = 0; mi < 2; ++mi)
#pragma unroll
      for (int reg = 0; reg < 4; ++reg) {
        const int m = m0 + mw + mi * 16 + lg * 4 + reg;
#pragma unroll
        for (int ni = 0; ni < 4; ++ni) {
          const int c = n0 + nw + ni * 16 + l16;
          outp[(size_t)m * N + c] = acc[mi][ni][reg];
        }
      }
  } else if (MODE == 1) {
    ushort_t* outp = (ushort_t*)out0;
#pragma unroll
    for (int mi = 0; mi < 2; ++mi)
#pragma unroll
      for (int reg = 0; reg < 4; ++reg) {
        const int m = m0 + mw + mi * 16 + lg * 4 + reg;
#pragma unroll
        for (int ni = 0; ni < 4; ++ni) {
          const int c = n0 + nw + ni * 16 + l16;
          float v = acc[mi][ni][reg] + b0p[c];
          outp[(size_t)m * N + c] = f32_bf16(fmaxf(v, 0.f));
        }
      }
  } else {
#pragma unroll
    for (int mi = 0; mi < 2; ++mi)
#pragma unroll
      for (int reg = 0; reg < 4; ++reg) {
        const int m = m0 + mw + mi * 16 + lg * 4 + reg;
        const int b = m >> 11, l = m & (L_ - 1);
#pragma unroll
        for (int ni = 0; ni < 4; ++ni) {
          const int c = n0 + nw + ni * 16 + l16;
          const int which = c >> 9, cc = c & 511;
          const int h = cc >> 6, dh = cc & 63;
          const float* bias = (which == 0) ? b0p : (which == 1) ? b1p : b2p;
          float v = acc[mi][ni][reg] + bias[cc];
          if (which == 0) {
            ((ushort_t*)out0)[(((size_t)b * H_ + h) * L_ + l) * DH_ + dh] =
                f32_bf16(v * 0.125f);                    // q pre-scaled
          } else if (which == 1) {
            ((ushort_t*)out1)[(((size_t)b * H_ + h) * L_ + l) * DH_ + dh] = f32_bf16(v);
          } else {
            ((ushort_t*)out2)[(((size_t)b * H_ + h) * DH_ + dh) * L_ + l] = f32_bf16(v);
          }
        }
      }
  }
}

// ---------------------------------------------------------------------------
// FFN2 split-K combine: out = out + p1 + bias
// ---------------------------------------------------------------------------
__global__ __launch_bounds__(256)
void ffn2_add(float* __restrict__ out, const float* __restrict__ p1,
              const float* __restrict__ bias) {
  int i = (blockIdx.x * 256 + threadIdx.x) * 4;
  float4 a = *(const float4*)(out + i);
  float4 b = *(const float4*)(p1 + i);
  float4 bb = *(const float4*)(bias + (i & (D_ - 1)));
  a.x += b.x + bb.x; a.y += b.y + bb.y;
  a.z += b.z + bb.z; a.w += b.w + bb.w;
  *(float4*)(out + i) = a;
}

// ---------------------------------------------------------------------------
// MFMA flash attention (unchanged from R9): S^T form, dbuf K/V DMA,
// reg-prefetched E, longest-first dispatch, bf16 ring, bf16 partials.
// ---------------------------------------------------------------------------
__global__ __launch_bounds__(256, 3)
void attn_mfma(const ushort_t* __restrict__ q16, const ushort_t* __restrict__ k16,
               const ushort_t* __restrict__ vT, const ushort_t* __restrict__ relb,
               ushort_t* __restrict__ Opart, float* __restrict__ Lpart) {
  __shared__ ushort_t Ks[2][64 * 64];   // [j][dh], 16B chunks swizzled by (j&7)
  __shared__ ushort_t Vs[2][64 * 64];   // [dh][j], 16B chunks swizzled by (dh&7)
  __shared__ ushort_t Rc[64 * 136];     // ring [qrow][col]; 128 cols + pad

  const int t   = threadIdx.x;
  const int wv  = t >> 6;
  const int ln  = t & 63;
  const int l16 = ln & 15;
  const int lg  = ln >> 4;
  const int bh  = blockIdx.x;
  const int yy  = blockIdx.y;
  const int qb  = 31 - ((yy < 16) ? yy : (47 - yy));   // longest blocks first
  const int z   = blockIdx.z;
  const int i0  = qb * 64;
  const int mid = (qb + 2) >> 1;
  const int kbeg = z ? mid : 0;
  const int kend = z ? (qb + 1) : mid;

  const ushort_t* qh = q16 + (size_t)bh * L_ * DH_;
  const ushort_t* kh = k16 + (size_t)bh * L_ * DH_;
  const ushort_t* vh = vT + (size_t)bh * DH_ * L_;
  const ushort_t* relh = relb + (bh & 7) * DH_;

  const int r64i = wv * 16 + l16;
  const int rrow = r64i * 136;

  bf16x8 qf0, qf1;
  {
    const ushort_t* qr = qh + (size_t)(i0 + r64i) * DH_ + lg * 8;
    qf0 = *(const bf16x8*)(qr);
    qf1 = *(const bf16x8*)(qr + 32);
  }

  const f32x4 zf = {0.f, 0.f, 0.f, 0.f};
  f32x4 Of[4] = {zf, zf, zf, zf};
  float lsum = 0.f;
  bf16x8 eA[4], eB[4];

  auto stageKV = [&](int j0, int b) {
#pragma unroll
    for (int i = 0; i < 2; ++i) {
      const int s = (i * 4 + wv) * 64 + ln;
      const int row = s >> 3, c = s & 7;
      const int g = c ^ (row & 7);
      gl_lds16(kh + (size_t)(j0 + row) * DH_ + g * 8, &Ks[b][(i * 4 + wv) * 512]);
      gl_lds16(vh + (size_t)row * L_ + j0 + g * 8, &Vs[b][(i * 4 + wv) * 512]);
    }
  };

  auto load_E = [&](int mbase) {
#pragma unroll
    for (int cb = 0; cb < 4; ++cb) {
      const ushort_t* e = relh + (size_t)(mbase + cb * 16 + l16) * D_ + lg * 8;
      eA[cb] = *(const bf16x8*)(e);
      eB[cb] = *(const bf16x8*)(e + 32);
    }
  };

  auto mfma_R = [&](int slotbase) {
#pragma unroll
    for (int cb = 0; cb < 4; ++cb) {
      f32x4 r = MFMA32(eA[cb], qf0, zf);
      r = MFMA32(eB[cb], qf1, r);
      ushort4 w;
      w.x = f32_bf16(r[0]); w.y = f32_bf16(r[1]);
      w.z = f32_bf16(r[2]); w.w = f32_bf16(r[3]);
      *(ushort4*)&Rc[rrow + slotbase + cb * 16 + lg * 4] = w;
      if (slotbase == 0 && cb == 0 && lg == 0)
        *(ushort4*)&Rc[rrow + 128] = w;   // pad cols 128..131 = ring cols 0..3
    }
  };

  if (kbeg < kend) {
    load_E(L_ - 64 - i0 + kbeg * 64);
    stageKV(kbeg * 64, kbeg & 1);
    mfma_R((kbeg & 1) * 64);
    if (kbeg < qb) load_E(L_ - 64 - i0 + (kbeg + 1) * 64);

    for (int kb = kbeg; kb < kend; ++kb) {
      const int j0 = kb * 64;
      const int buf = kb & 1;
      __syncthreads();
      if (kb + 1 < kend) stageKV(j0 + 64, buf ^ 1);
      if (kb < qb) mfma_R(((kb + 1) & 1) * 64);
      if (kb + 1 < qb) load_E(L_ - 64 - i0 + (kb + 2) * 64);

      f32x4 sf[4];
#pragma unroll
      for (int cb = 0; cb < 4; ++cb) {
        const int j = cb * 16 + l16;
        const int sw = j & 7;
        bf16x8 k0 = *(const bf16x8*)&Ks[buf][j * 64 + ((lg ^ sw) * 8)];
        bf16x8 k1 = *(const bf16x8*)&Ks[buf][j * 64 + (((lg + 4) ^ sw) * 8)];
        f32x4 s = MFMA32(k0, qf0, zf);
        sf[cb] = MFMA32(k1, qf1, s);
      }

      const bool diag = (kb == qb);
      bf16x4 pa[4];
#pragma unroll
      for (int cb = 0; cb < 4; ++cb) {
        const int jj0 = cb * 16 + lg * 4;
        const int base = (j0 + jj0 + 63 - r64i) & 127;
        union { bf16x4 v; ushort_t s[4]; } pk;
#pragma unroll
        for (int reg = 0; reg < 4; ++reg) {
          float x = sf[cb][reg] + bf16_f32(Rc[rrow + base + reg]);
          if (diag && (jj0 + reg) > r64i) x = -1e30f;
          float p = __expf(x);
          lsum += p;
          pk.s[reg] = f32_bf16(p);
        }
        pa[cb] = pk.v;
      }

#pragma unroll
      for (int cb2 = 0; cb2 < 4; ++cb2) {
        const int dh = cb2 * 16 + l16;
        const int sw = dh & 7;
        const ushort_t* vrow = &Vs[buf][dh * 64];
#pragma unroll
        for (int cb = 0; cb < 4; ++cb) {
          const int cc = cb * 2 + (lg >> 1);
          bf16x4 vf = *(const bf16x4*)&vrow[((cc ^ sw) * 8) + (lg & 1) * 4];
          Of[cb2] = MFMA16(vf, pa[cb], Of[cb2]);
        }
      }
    }
  }

  float tot = lsum;
  tot += __shfl_xor(tot, 16);
  tot += __shfl_xor(tot, 32);
  if (lg == 0)
    Lpart[((size_t)(z * 16 + bh)) * L_ + i0 + r64i] = tot;
  ushort_t* orow = Opart + (((size_t)(z * 16 + bh)) * L_ + i0 + r64i) * DH_;
#pragma unroll
  for (int cb2 = 0; cb2 < 4; ++cb2) {
    ushort4 w;
    w.x = f32_bf16(Of[cb2][0]); w.y = f32_bf16(Of[cb2][1]);
    w.z = f32_bf16(Of[cb2][2]); w.w = f32_bf16(Of[cb2][3]);
    *(ushort4*)&orow[cb2 * 16 + lg * 4] = w;
  }
}

// ---------------------------------------------------------------------------
// attn partial combine: attnb = (O0 + O1) / (l0 + l1), bf16 (B,L,D). grid 2048.
// ---------------------------------------------------------------------------
__global__ __launch_bounds__(256)
void attn_combine(const ushort_t* __restrict__ Opart, const float* __restrict__ Lpart,
                  ushort_t* __restrict__ attnb) {
  const int g = blockIdx.x * 256 + threadIdx.x;
  const int dh4 = g & 15, i = (g >> 4) & (L_ - 1), bh = g >> 15;
  const size_t o0 = (((size_t)bh * L_ + i) * DH_) + dh4 * 4;
  const size_t zs = (size_t)16 * L_ * DH_;
  ushort4 a = *(const ushort4*)(Opart + o0);
  ushort4 b = *(const ushort4*)(Opart + o0 + zs);
  const float l = Lpart[(size_t)bh * L_ + i] + Lpart[(size_t)(16 + bh) * L_ + i];
  const float inv = 1.f / l;
  ushort4 o;
  o.x = f32_bf16((bf16_f32(a.x) + bf16_f32(b.x)) * inv);
  o.y = f32_bf16((bf16_f32(a.y) + bf16_f32(b.y)) * inv);
  o.z = f32_bf16((bf16_f32(a.z) + bf16_f32(b.z)) * inv);
  o.w = f32_bf16((bf16_f32(a.w) + bf16_f32(b.w)) * inv);
  const int bb = bh >> 3, h = bh & 7;
  *(ushort4*)(attnb + ((size_t)(bb * L_ + i)) * D_ + h * DH_ + dh4 * 4) = o;
}

// ---------------------------------------------------------------------------
extern "C" void kernel_launch(void* const* d_in, const int* in_sizes, int n_in,
                              void* d_out, int out_size, void* d_ws, size_t ws_size,
                              hipStream_t stream) {
  const float* x   = (const float*)d_in[0];
  const float* wq  = (const float*)d_in[2];
  const float* bq  = (const float*)d_in[3];
  const float* wk  = (const float*)d_in[4];
  const float* bk  = (const float*)d_in[5];
  const float* wv  = (const float*)d_in[6];
  const float* bv  = (const float*)d_in[7];
  const float* rel = (const float*)d_in[8];
  const float* w1  = (const float*)d_in[9];
  const float* b1  = (const float*)d_in[10];
  const float* w2  = (const float*)d_in[11];
  const float* b2  = (const float*)d_in[12];

  char* wsb = (char*)d_ws;
  const size_t MB = 1u << 20;
  ushort_t* xb     = (ushort_t*)(wsb + 0 * MB);    // 4 MB; dead after QKV
  ushort_t* attnb  = (ushort_t*)(wsb + 0 * MB);    // 4 MB; aliases xb
  ushort_t* wqkvT  = (ushort_t*)(wsb + 4 * MB);    // 1.5 MB
  ushort_t* w1T    = (ushort_t*)(wsb + 6 * MB);    // 2 MB
  ushort_t* w2T    = (ushort_t*)(wsb + 8 * MB);    // 2 MB
  ushort_t* relb   = (ushort_t*)(wsb + 10 * MB);   // 2 MB
  ushort_t* q16    = (ushort_t*)(wsb + 12 * MB);   // 4 MB (B,H,L,DH)
  ushort_t* k16    = (ushort_t*)(wsb + 16 * MB);   // 4 MB
  ushort_t* vTb    = (ushort_t*)(wsb + 20 * MB);   // 4 MB (B,H,DH,L)
  ushort_t* Opart  = (ushort_t*)(wsb + 24 * MB);   // 8 MB (2,16,L,DH) bf16
  float*    Lpart  = (float*)(wsb + 40 * MB);      // 256 KB (2,16,L) f32
  ushort_t* hidb   = (ushort_t*)(wsb + 24 * MB);   // 16 MB; clobbers dead Opart
  float*    p1     = (float*)(wsb + 12 * MB);      // 8 MB; clobbers dead q16/k16
  float*    out    = (float*)d_out;

  dim3 blk(256);
  pack_all<<<dim3(2240), blk, 0, stream>>>(x, rel, wq, wk, wv, w1, w2,
                                           xb, relb, wqkvT, w1T, w2T);
  // fused QKV projection; emits q (scaled), k, and v already transposed
  gemm_mfma<2><<<dim3(12, 64), blk, 0, stream>>>(
      xb, wqkvT, bq, bk, bv, q16, k16, vTb, B_ * L_, 1536, D_, 1);
  attn_mfma<<<dim3(16, 32, 2), blk, 0, stream>>>(q16, k16, vTb, relb, Opart, Lpart);
  attn_combine<<<dim3(2048), blk, 0, stream>>>(Opart, Lpart, attnb);
  gemm_mfma<1><<<dim3(16, 64), blk, 0, stream>>>(
      attnb, w1T, b1, nullptr, nullptr, hidb, nullptr, nullptr,
      B_ * L_, DFC_, D_, 1);
  gemm_mfma<0><<<dim3(4, 64, 2), blk, 0, stream>>>(
      hidb, w2T, nullptr, nullptr, nullptr, out, p1, nullptr,
      B_ * L_, D_, DFC_, 2);
  ffn2_add<<<dim3(2048), blk, 0, stream>>>(out, p1, b2);
}